// Round 7
// baseline (244.221 us; speedup 1.0000x reference)
//
#include <hip/hip_runtime.h>
#include <hip/hip_bf16.h>

// GCN layer: out = relu( A0 @ (X W0) + A1 @ (X W1) + bias )
// N=50000, D=128, E=800000 per adjacency, fp32 in/out, COO edges.
//
// R20 (this round):
//   prep        verbatim (wt transpose + cur zero; must precede mid on stream).
//   mid_kernel  RE-fusion of gemm+fill, occupancy-fixed: fill role LDS cut to
//               34.1 KB (FT7=2048; bin counters/cursors packed 2x16-bit per
//               int -- field adds are carry-safe, each field <= 2048; only g
//               stored per bucket, gpos/glim recomputed). Union with gemm
//               27.6 KB = 34.9 KB -> 4 blocks/CU for BOTH roles (R14's
//               failure was 70 KB union -> 2 blocks/CU for gemm). Gemm role
//               reloads B per m-tile (no VGPR arrays) to fit (512,8) bounds.
//               Saves one launch gap + overlaps independent fill/gemm work.
//   aggregate9  verbatim champion revert (62.5us). LEDGER CLOSED after 5
//               variants: agg9 62.5/177MB/31%V | agg11 65.9/157/51 |
//               agg12 67.4/177/48 | agg13 65.0/159/49. Model: dur ~=
//               max(missB/3.3TB/s, VALU) + sort. Random-gather miss path
//               pinned ~3.3TB/s across all structures/occupancies/phasings;
//               every FETCH cut cost more VALU than it saved. Do not touch.
// NEVER use fp32 LDS atomics in the per-record loop (R4: 1234us, R9: 1216us).
// NEVER duplicate the bucket sort across blocks (R17). Occupancy raises alone
// do nothing (R15, R18): gather is NOT latency-capacity-bound.
// NOTE: dur_us carries ~85us fixed overhead + ~7us run noise.

#define BROWS 32                   // bucket = 32 dst rows
#define NBUCK 1563                 // ceil(50000/32)
#define NB2 2048                   // padded bin count
#define BCAP 704                   // records per (bucket,adj); mean 512, +8.5 sigma
#define ACAP (2 * BCAP)
#define FT7 2048                   // fused-fill tile (edges per block) = 512 thr * 4
#define PREROWS 65536              // adj stride in unified pre

typedef __attribute__((ext_vector_type(8))) short bf16x8;
typedef __attribute__((ext_vector_type(4))) float f32x4;

__device__ inline unsigned short f2bf(float f) {
    union { float f; unsigned u; } v; v.f = f;
    unsigned r = v.u + 0x7fff + ((v.u >> 16) & 1);   // round-nearest-even
    return (unsigned short)(r >> 16);
}

// blocks 0..7: W transpose (4 k-slices x 2 Ws). block 8: zero cur.
__global__ __launch_bounds__(256) void prep_kernel(
    const float* __restrict__ W0, const float* __restrict__ W1,
    unsigned short* __restrict__ wt0, unsigned short* __restrict__ wt1,
    int* __restrict__ cur, int ncur)
{
    const int bid = blockIdx.x;
    const int tid = threadIdx.x;
    if (bid >= 8) {
        for (int i = tid; i < ncur; i += 256) cur[i] = 0;
        return;
    }
    const int which = bid >> 2;
    const int k0 = (bid & 3) * 32;
    const float* __restrict__ W = which ? W1 : W0;
    unsigned short* __restrict__ wt = which ? wt1 : wt0;
    for (int i = tid; i < 32 * 128; i += 256) {
        int k = k0 + (i >> 7), n = i & 127;
        wt[n * 128 + k] = f2bf(W[k * 128 + n]);
    }
}

// ---- fused mid kernel: fill role (34.1 KB) + gemm role (27.6 KB) ----
struct FillSM {
    int2 srt[FT7];                       // 16 KB sorted records
    int lcntp[NB2 / 2];                  // 4 KB: 2 x 16-bit counts per int
    int lcurp[NB2 / 2];                  // 4 KB: 2 x 16-bit cursors per int
    unsigned short skey[FT7];            // 4 KB bucket of each sorted record
    int gg[NBUCK];                       // 6.25 KB: global reserve offset g
    int wsum[8];
    int total;
};
struct GemmSM {
    unsigned short sA[64][136];          // bf16 A-tile (272B row)
    short ctile[8][16][40];              // per-wave 16x32 C tile (+pad)
};
union MidSM { FillSM f; GemmSM g; };     // 34.9 KB -> 4 blocks/CU

__device__ inline int pk_get(const int* p, int k) {
    return (int)(((unsigned)p[k >> 1] >> ((k & 1) * 16)) & 0xffffu);
}

__global__ __launch_bounds__(512, 8) void mid_kernel(
    const float* __restrict__ x,
    const unsigned short* __restrict__ wt0,
    const unsigned short* __restrict__ wt1,
    unsigned short* __restrict__ pre,    // unified: adj*PREROWS + row
    const int* __restrict__ ei0, const int* __restrict__ ei1,
    const float* __restrict__ ev0, const float* __restrict__ ev1,
    int* __restrict__ cur, int2* __restrict__ recs,
    int E, int N, int nfill)
{
    __shared__ MidSM sm;
    const int tid = threadIdx.x;
    const int bx = blockIdx.x;
    const int lane = tid & 63;
    const int wv = tid >> 6;

    if (bx < nfill) {
        // ================= fill role =================
        FillSM& F = sm.f;
        const int a = bx & 1;
        const int e0 = (bx >> 1) * FT7;
        const int* __restrict__ ei = a ? ei1 : ei0;
        const float* __restrict__ ev = a ? ev1 : ev0;

        ((int2*)F.lcntp)[tid] = make_int2(0, 0);   // 1024 ints = 512 int2
        __syncthreads();

        // load 4 consecutive edges per thread (int4/float4 vector loads)
        const int eb = e0 + tid * 4;
        int dd[4], ss[4]; float vv[4];
        if (e0 + FT7 <= E) {
            int4 d = *(const int4*)(ei + eb);
            int4 s = *(const int4*)(ei + E + eb);
            float4 v = *(const float4*)(ev + eb);
            dd[0] = d.x; dd[1] = d.y; dd[2] = d.z; dd[3] = d.w;
            ss[0] = s.x; ss[1] = s.y; ss[2] = s.z; ss[3] = s.w;
            vv[0] = v.x; vv[1] = v.y; vv[2] = v.z; vv[3] = v.w;
        } else {
#pragma unroll
            for (int j = 0; j < 4; ++j) {
                int e = eb + j;
                if (e < E) { dd[j] = ei[e]; ss[j] = ei[E + e]; vv[j] = ev[e]; }
            }
        }
        int key4[4]; int2 rec[4];
#pragma unroll
        for (int j = 0; j < 4; ++j) {
            if (eb + j < E) {
                key4[j] = dd[j] >> 5;
                rec[j] = make_int2(((dd[j] & 31) << 17) | (a << 16) | ss[j],
                                   __float_as_int(vv[j]));
                atomicAdd(&F.lcntp[key4[j] >> 1], 1 << ((key4[j] & 1) * 16));
            } else key4[j] = -1;
        }
        __syncthreads();

        // wave-shuffle exclusive scan over 2048 bins (4 per thread, packed)
        int p0 = F.lcntp[2 * tid], p1 = F.lcntp[2 * tid + 1];
        int cc[4] = { p0 & 0xffff, (int)((unsigned)p0 >> 16),
                      p1 & 0xffff, (int)((unsigned)p1 >> 16) };
        int tsum = cc[0] + cc[1] + cc[2] + cc[3];
        int p = tsum;
#pragma unroll
        for (int o = 1; o < 64; o <<= 1) {
            int t = __shfl_up(p, o);
            if (lane >= o) p += t;
        }
        if (lane == 63) F.wsum[wv] = p;
        __syncthreads();
        int wbase = 0;
#pragma unroll
        for (int w2 = 0; w2 < 7; ++w2) wbase += (w2 < wv) ? F.wsum[w2] : 0;
        if (tid == 511) F.total = wbase + p;
        int off = wbase + p - tsum;          // exclusive start of bin 4*tid
        const int k0 = 4 * tid;
        // packed cursor init + global reservations
        F.lcurp[2 * tid]     = off | ((off + cc[0]) << 16);
        F.lcurp[2 * tid + 1] = (off + cc[0] + cc[1]) |
                               ((off + cc[0] + cc[1] + cc[2]) << 16);
#pragma unroll
        for (int h = 0; h < 4; ++h) {
            int k = k0 + h;
            if (k < NBUCK && cc[h] > 0) {
                int bin = k * 2 + a;
                F.gg[k] = atomicAdd(&cur[bin], cc[h]);
            }
        }
        __syncthreads();

        // scatter into LDS sorted by bucket (packed cursor atomics)
#pragma unroll
        for (int j = 0; j < 4; ++j) {
            if (key4[j] >= 0) {
                int sh = (key4[j] & 1) * 16;
                unsigned old = atomicAdd(&F.lcurp[key4[j] >> 1], 1 << sh);
                int pp = (old >> sh) & 0xffff;
                F.srt[pp] = rec[j];
                F.skey[pp] = (unsigned short)key4[j];
            }
        }
        __syncthreads();

        // coalesced write-out; start[k] == cursor[k-1] (ends are next starts)
        const int total = F.total;
        for (int i = tid; i < total; i += 512) {
            int k = F.skey[i];
            int st = k ? pk_get(F.lcurp, k - 1) : 0;
            int r = i - st;
            int g = F.gg[k];
            int lim = BCAP - g; if (lim < 0) lim = 0;    // overflow guard
            if (r < lim) recs[(k * 2 + a) * BCAP + g + r] = F.srt[i];
        }
    } else {
        // ================= gemm role (R16 64-row tile, B reloaded per mt) ===
        GemmSM& G = sm.g;
        const int m0 = (bx - nfill) * 64;

        // stage A: 64 rows x 32 float4; 4 float4 per thread, guarded
#pragma unroll
        for (int t = 0; t < 4; ++t) {
            int idx = t * 512 + tid;
            int r = idx >> 5;                 // 0..63
            int c4 = (idx & 31) << 2;
            if (m0 + r < N) {
                float4 v = *(const float4*)&x[(size_t)(m0 + r) * 128 + c4];
                ushort4 s;
                s.x = f2bf(v.x); s.y = f2bf(v.y); s.z = f2bf(v.z); s.w = f2bf(v.w);
                *(ushort4*)&G.sA[r][c4] = s;
            }
        }
        __syncthreads();

        const int adj = wv >> 2;
        const int wq = wv & 3;
        const unsigned short* __restrict__ wt = adj ? wt1 : wt0;
        unsigned short* __restrict__ po = pre + (size_t)adj * PREROWS * 128;
        const int l15 = lane & 15;
        const int quad = lane >> 4;
        const int nA = wq * 32 + l15;
        const int rr = lane >> 2, cg = (lane & 3) * 8;

#pragma unroll
        for (int mt = 0; mt < 4; ++mt) {
            f32x4 c0 = {0.f, 0.f, 0.f, 0.f};
            f32x4 c1 = {0.f, 0.f, 0.f, 0.f};
#pragma unroll
            for (int kk = 0; kk < 4; ++kk) {
                union { bf16x8 v; ushort4 h[2]; } au;
                au.h[0] = *(const ushort4*)&G.sA[mt * 16 + l15][kk * 32 + quad * 8];
                au.h[1] = *(const ushort4*)&G.sA[mt * 16 + l15][kk * 32 + quad * 8 + 4];
                bf16x8 b0 = *(const bf16x8*)&wt[nA * 128 + kk * 32 + quad * 8];
                bf16x8 b1 = *(const bf16x8*)&wt[(nA + 16) * 128 + kk * 32 + quad * 8];
                c0 = __builtin_amdgcn_mfma_f32_16x16x32_bf16(au.v, b0, c0, 0, 0, 0);
                c1 = __builtin_amdgcn_mfma_f32_16x16x32_bf16(au.v, b1, c1, 0, 0, 0);
            }
            // stage C into wave-private LDS tile (wave-internal dep: no barrier)
#pragma unroll
            for (int i = 0; i < 4; ++i) {
                G.ctile[wv][quad * 4 + i][l15]      = (short)f2bf(c0[i]);
                G.ctile[wv][quad * 4 + i][16 + l15] = (short)f2bf(c1[i]);
            }
            int row = m0 + mt * 16 + rr;
            if (row < N) {
                int4 sv = *(const int4*)&G.ctile[wv][rr][cg];   // 16B aligned
                *(int4*)&po[(size_t)row * 128 + wq * 32 + cg] = sv;
            }
        }
    }
}

// One block per 32-row bucket (256 thr = 4 waves, wave wv -> rows wv*8..+7).
// Stage records in LDS, counting-sort FULL records by row (32 keys), then
// 8x-unrolled independent gathers from the unified pre, register accumulate,
// fused bias+relu writeout. (Verbatim champion: measured 62.3-62.7us.)
__global__ __launch_bounds__(256, 6) void aggregate9_kernel(
    const int* __restrict__ cur, const int2* __restrict__ recs,
    const unsigned short* __restrict__ pre,
    const float* __restrict__ bias,
    float* __restrict__ out, int N)
{
    __shared__ int2 srec[ACAP];             // 11.3 KB staged raw
    __shared__ int2 srt[ACAP];              // 11.3 KB row-sorted
    __shared__ int lcnt[32];
    __shared__ int lstart[32];
    __shared__ int lcur[32];

    const int b = blockIdx.x;
    const int tid = threadIdx.x;

    int n0 = cur[2 * b];     if (n0 > BCAP) n0 = BCAP;
    int n1 = cur[2 * b + 1]; if (n1 > BCAP) n1 = BCAP;
    const int total = n0 + n1;
    const int base0 = (2 * b) * BCAP, base1 = (2 * b + 1) * BCAP;

    if (tid < 32) lcnt[tid] = 0;
    __syncthreads();

    // stage + per-row counts (int LDS atomics)
    for (int i = tid; i < total; i += 256) {
        int2 r = (i < n0) ? recs[base0 + i] : recs[base1 + i - n0];
        srec[i] = r;
        atomicAdd(&lcnt[(r.x >> 17) & 31], 1);
    }
    __syncthreads();

    // wave 0 lanes 0-31: shfl exclusive scan of 32 counters
    if (tid < 32) {
        int cme = lcnt[tid];
        int p = cme;
#pragma unroll
        for (int o = 1; o < 32; o <<= 1) {
            int t = __shfl_up(p, o);
            if (tid >= o) p += t;
        }
        lstart[tid] = p - cme;
        lcur[tid] = p - cme;
    }
    __syncthreads();

    // scatter full records sorted by row
    for (int i = tid; i < total; i += 256) {
        int2 r = srec[i];
        srt[atomicAdd(&lcur[(r.x >> 17) & 31], 1)] = r;
    }
    __syncthreads();

    // gather: wave wv owns rows wv*8 .. wv*8+7; both adjacencies in one run
    const int wv = tid >> 6;
    const int lane = tid & 63;
    const float2 bi = *(const float2*)&bias[lane * 2];

#define GA(r) (*(const unsigned*)&pre[((r).x & 0x1ffff) * 128 + 2 * lane])
#define ACC(r, u) { float v = __int_as_float((r).y);                    \
        acc.x = fmaf(v, __uint_as_float((u) << 16), acc.x);             \
        acc.y = fmaf(v, __uint_as_float((u) & 0xffff0000u), acc.y); }

    for (int t = 0; t < 8; ++t) {
        const int rl = wv * 8 + t;
        const int s = lstart[rl];
        const int e = s + lcnt[rl];
        float2 acc = make_float2(0.f, 0.f);
        int j = s;
        for (; j + 8 <= e; j += 8) {
            int2 r0 = srt[j], r1 = srt[j + 1], r2 = srt[j + 2], r3 = srt[j + 3];
            int2 r4 = srt[j + 4], r5 = srt[j + 5], r6 = srt[j + 6], r7 = srt[j + 7];
            unsigned u0 = GA(r0), u1 = GA(r1), u2 = GA(r2), u3 = GA(r3);
            unsigned u4 = GA(r4), u5 = GA(r5), u6 = GA(r6), u7 = GA(r7);
            ACC(r0, u0); ACC(r1, u1); ACC(r2, u2); ACC(r3, u3);
            ACC(r4, u4); ACC(r5, u5); ACC(r6, u6); ACC(r7, u7);
        }
        for (; j + 4 <= e; j += 4) {
            int2 r0 = srt[j], r1 = srt[j + 1], r2 = srt[j + 2], r3 = srt[j + 3];
            unsigned u0 = GA(r0), u1 = GA(r1), u2 = GA(r2), u3 = GA(r3);
            ACC(r0, u0); ACC(r1, u1); ACC(r2, u2); ACC(r3, u3);
        }
        for (; j < e; ++j) {
            int2 r0 = srt[j];
            unsigned u0 = GA(r0);
            ACC(r0, u0);
        }
        int row = b * BROWS + rl;
        if (row < N) {
            float2 o;
            o.x = fmaxf(acc.x + bi.x, 0.f);
            o.y = fmaxf(acc.y + bi.y, 0.f);
            *(float2*)&out[row * 128 + 2 * lane] = o;
        }
    }
#undef GA
#undef ACC
}

extern "C" void kernel_launch(void* const* d_in, const int* in_sizes, int n_in,
                              void* d_out, int out_size, void* d_ws, size_t ws_size,
                              hipStream_t stream) {
    const float* x    = (const float*)d_in[0];
    const float* W0   = (const float*)d_in[1];
    const float* W1   = (const float*)d_in[2];
    const float* bias = (const float*)d_in[3];
    const float* ev0  = (const float*)d_in[4];
    const float* ev1  = (const float*)d_in[5];
    const int*   ei0  = (const int*)d_in[6];
    const int*   ei1  = (const int*)d_in[7];
    float* out = (float*)d_out;

    const int N = in_sizes[0] / 128;      // 50000
    const int E = in_sizes[4];            // 800000
    const int NBINS2 = NBUCK * 2;         // 3126

    // Workspace layout
    char* w = (char*)d_ws;
    unsigned short* pre = (unsigned short*)w;   w += (size_t)2 * PREROWS * 128 * 2;  // 33.5 MB
    unsigned short* wt0 = (unsigned short*)w;   w += (size_t)128 * 128 * 2;
    unsigned short* wt1 = (unsigned short*)w;   w += (size_t)128 * 128 * 2;
    int* cur = (int*)w;                         w += (size_t)NBINS2 * 4;
    int2* recs = (int2*)w;                      w += (size_t)NBINS2 * BCAP * 8;      // 17.6 MB

    // Phase 0: W -> bf16 transposed + zero cur (one 9-block dispatch)
    prep_kernel<<<9, 256, 0, stream>>>(W0, W1, wt0, wt1, cur, NBINS2);

    // Phase 1+2 fused: fill (34.1 KB) + gemm (27.6 KB) roles, 4 blocks/CU both
    const int nfill = 2 * ((E + FT7 - 1) / FT7);      // 782
    const int ngemm = (N + 63) / 64;                   // 782
    mid_kernel<<<nfill + ngemm, 512, 0, stream>>>(
        x, wt0, wt1, pre, ei0, ei1, ev0, ev1, cur, recs, E, N, nfill);

    // Phase 3: bucket-sorted gather aggregation + bias + relu (champion)
    aggregate9_kernel<<<NBUCK, 256, 0, stream>>>(cur, recs, pre, bias, out, N);
}

// Round 8
// 201.563 us; speedup vs baseline: 1.2116x; 1.2116x over previous
//
#include <hip/hip_runtime.h>
#include <hip/hip_bf16.h>

// GCN layer: out = relu( A0 @ (X W0) + A1 @ (X W1) + bias )
// N=50000, D=128, E=800000 per adjacency, fp32 in/out, COO edges.
//
// R21: FULL REVERT to the twice-measured champion configuration (R13:
// 201.3 / 205.3 us). Eight rounds of restructuring all regressed or landed
// in the +-7us noise band:
//   fusion v1 (R14, 70KB union -> 2 blk/CU):        pair 57 -> 72us
//   fusion v2 (R20, FT=2048 + packed counters):     pair 57 -> 94us
//     (write-out degenerates: 1.3 rec/bucket -> ~random 8B stores,
//      WRITE 66->81MB; scan cost per edge doubles. Fusion is DEAD: LDS
//      budget cannot give FT>=4096 AND >=4 blk/CU simultaneously.)
//   aggregate variants: agg10 64.1 | agg11 65.9 | agg12 67.4 | agg13 65.0
//     vs agg9 62.5. Model: dur ~= max(missB/3.3TB/s, VALU) + sort.
//     Random-gather miss path pinned ~3.3TB/s across 5 structures,
//     3 occupancy levels, 2 phasings. FETCH cuts always cost more VALU.
//   re-tilings (gemm64/fill6, R16/R19): 210.7/214.3 = noise vs 205.3.
// Budget: ~85us fixed harness overhead (invariant to launch count) +
// 62.5us aggregate (pinned) + ~57us serial middle (floor ~15us, but the
// only overlap mechanism -- fusion -- has two structural disproofs).
// NEVER use fp32 LDS atomics in the per-record loop (R4: 1234us, R9: 1216us).

#define BROWS 32                   // bucket = 32 dst rows
#define NBUCK 1563                 // ceil(50000/32)
#define NB2 2048                   // padded bin count for fill5 scan
#define BCAP 704                   // records per (bucket,adj); mean 512, +8.5 sigma
#define ACAP (2 * BCAP)
#define FT5 8192                   // fill tile (edges per block)
#define PREROWS 65536              // adj stride in unified pre

typedef __attribute__((ext_vector_type(8))) short bf16x8;
typedef __attribute__((ext_vector_type(4))) float f32x4;

__device__ inline unsigned short f2bf(float f) {
    union { float f; unsigned u; } v; v.f = f;
    unsigned r = v.u + 0x7fff + ((v.u >> 16) & 1);   // round-nearest-even
    return (unsigned short)(r >> 16);
}

// blocks 0..7: W transpose (4 k-slices x 2 Ws). block 8: zero cur.
__global__ __launch_bounds__(256) void prep_kernel(
    const float* __restrict__ W0, const float* __restrict__ W1,
    unsigned short* __restrict__ wt0, unsigned short* __restrict__ wt1,
    int* __restrict__ cur, int ncur)
{
    const int bid = blockIdx.x;
    const int tid = threadIdx.x;
    if (bid >= 8) {
        for (int i = tid; i < ncur; i += 256) cur[i] = 0;
        return;
    }
    const int which = bid >> 2;
    const int k0 = (bid & 3) * 32;
    const float* __restrict__ W = which ? W1 : W0;
    unsigned short* __restrict__ wt = which ? wt1 : wt0;
    for (int i = tid; i < 32 * 128; i += 256) {
        int k = k0 + (i >> 7), n = i & 127;
        wt[n * 128 + k] = f2bf(W[k * 128 + n]);
    }
}

// One block: 16 x-rows, BOTH adjacencies. Waves 0-3 -> W0 cols, 4-7 -> W1.
// Block stages x rows fp32->bf16 into LDS once; waves ds_read A-frags.
// A: m=lane&15, k=quad*8+j ; B(from Wt): n=lane&15, k=quad*8+j ;
// C/D: col=lane&15, row=quad*4+reg. C staged via LDS -> 16-B global stores.
__global__ __launch_bounds__(512) void gemm_fused_kernel(
    const float* __restrict__ x,
    const unsigned short* __restrict__ wt0,
    const unsigned short* __restrict__ wt1,
    unsigned short* __restrict__ pre,    // unified: adj*PREROWS + row
    int N)
{
    __shared__ unsigned short sA[16][136];  // bf16 A-tile, pad: 272B row (2-way banks)
    __shared__ short ctile[8][16][40];      // per-wave 16x32 C tile (+pad)

    const int tid = threadIdx.x;
    const int m0 = blockIdx.x * 16;

    // stage A: 512 float4 loads (1 per thread), convert, store 8B to LDS
    {
        int r = tid >> 5;                 // 32 float4 per row
        int c4 = (tid & 31) << 2;
        float4 v = *(const float4*)&x[(m0 + r) * 128 + c4];
        ushort4 s;
        s.x = f2bf(v.x); s.y = f2bf(v.y); s.z = f2bf(v.z); s.w = f2bf(v.w);
        *(ushort4*)&sA[r][c4] = s;
    }
    __syncthreads();

    const int w = tid >> 6;
    const int lane = tid & 63;
    const int adj = w >> 2;
    const int wq = w & 3;
    const unsigned short* __restrict__ wt = adj ? wt1 : wt0;
    unsigned short* __restrict__ po = pre + (size_t)adj * PREROWS * 128;
    const int l15 = lane & 15;
    const int quad = lane >> 4;
    const int nA = wq * 32 + l15;

    f32x4 c0 = {0.f, 0.f, 0.f, 0.f};
    f32x4 c1 = {0.f, 0.f, 0.f, 0.f};
#pragma unroll
    for (int k0 = 0; k0 < 128; k0 += 32) {
        union { bf16x8 v; ushort4 h[2]; } au;
        au.h[0] = *(const ushort4*)&sA[l15][k0 + quad * 8];
        au.h[1] = *(const ushort4*)&sA[l15][k0 + quad * 8 + 4];
        bf16x8 b0 = *(const bf16x8*)&wt[nA * 128 + k0 + quad * 8];
        bf16x8 b1 = *(const bf16x8*)&wt[(nA + 16) * 128 + k0 + quad * 8];
        c0 = __builtin_amdgcn_mfma_f32_16x16x32_bf16(au.v, b0, c0, 0, 0, 0);
        c1 = __builtin_amdgcn_mfma_f32_16x16x32_bf16(au.v, b1, c1, 0, 0, 0);
    }

    // stage C into wave-private LDS tile (wave-internal dep: no barrier)
#pragma unroll
    for (int i = 0; i < 4; ++i) {
        ctile[w][quad * 4 + i][l15]      = (short)f2bf(c0[i]);
        ctile[w][quad * 4 + i][16 + l15] = (short)f2bf(c1[i]);
    }
    const int rr = lane >> 2, cg = (lane & 3) * 8;
    ushort4 s0 = *(ushort4*)&ctile[w][rr][cg];
    ushort4 s1 = *(ushort4*)&ctile[w][rr][cg + 4];
    int row = m0 + rr;                        // N % 16 == 0, always < N
    *(ushort4*)&po[row * 128 + wq * 32 + cg] = s0;
    *(ushort4*)&po[row * 128 + wq * 32 + cg + 4] = s1;
}

// LDS counting-sort fill: block sorts its 8192 edges by bucket (dst>>5) in
// LDS, reserves one global range per (block,bucket), then writes out with
// consecutive threads at consecutive global addresses (coalesced runs).
// Record = { rl<<17 | adj<<16 | src, val }; bin = bucket*2 + adj.
__global__ __launch_bounds__(1024) void fill5_kernel(
    const int* __restrict__ ei0, const int* __restrict__ ei1,
    const float* __restrict__ ev0, const float* __restrict__ ev1,
    int* __restrict__ cur, int2* __restrict__ recs, int E)
{
    __shared__ int2 srt[FT5];                 // 64 KB sorted records
    __shared__ unsigned short skey[FT5];      // 16 KB bucket of each record
    __shared__ int lcnt[NB2];                 // 8 KB
    __shared__ int bstart[NB2];               // 8 KB
    __shared__ int lcur[NB2];                 // 8 KB
    __shared__ int gpos[NBUCK];               // 6.3 KB global base per bucket
    __shared__ int glim[NBUCK];               // 6.3 KB
    __shared__ int part[1024];                // 4 KB scan partials

    const int a = blockIdx.y;
    const int* __restrict__ ei = a ? ei1 : ei0;
    const float* __restrict__ ev = a ? ev1 : ev0;
    const int tid = threadIdx.x;
    const int e0 = blockIdx.x * FT5;

    lcnt[tid] = 0; lcnt[tid + 1024] = 0;
    __syncthreads();

    int2 rec[8];
    int key8[8];
#pragma unroll
    for (int j = 0; j < 8; ++j) {
        int e = e0 + j * 1024 + tid;
        if (e < E) {
            int d = ei[e];
            int s = ei[E + e];
            key8[j] = d >> 5;
            rec[j] = make_int2(((d & 31) << 17) | (a << 16) | s,
                               __float_as_int(ev[e]));
            atomicAdd(&lcnt[key8[j]], 1);
        } else key8[j] = -1;
    }
    __syncthreads();

    // exclusive scan over 2048 bins (2 per thread)
    int c0 = lcnt[2 * tid], c1 = lcnt[2 * tid + 1];
    int tsum = c0 + c1;
    part[tid] = tsum;
    __syncthreads();
    for (int o = 1; o < 1024; o <<= 1) {
        int t = (tid >= o) ? part[tid - o] : 0;
        __syncthreads();
        part[tid] += t;
        __syncthreads();
    }
    int run = part[tid] - tsum;
    const int total = part[1023];
    bstart[2 * tid] = run; lcur[2 * tid] = run;
    bstart[2 * tid + 1] = run + c0; lcur[2 * tid + 1] = run + c0;

    // reserve global ranges (one atomic per nonzero (block,bucket))
#pragma unroll
    for (int h = 0; h < 2; ++h) {
        int k = 2 * tid + h;
        int c = h ? c1 : c0;
        if (k < NBUCK && c > 0) {
            int bin = k * 2 + a;
            int g = atomicAdd(&cur[bin], c);
            int lim = BCAP - g; if (lim < 0) lim = 0;    // overflow guard
            gpos[k] = bin * BCAP + g;
            glim[k] = lim;
        }
    }
    __syncthreads();

    // scatter into LDS sorted by bucket
#pragma unroll
    for (int j = 0; j < 8; ++j) {
        if (key8[j] >= 0) {
            int p = atomicAdd(&lcur[key8[j]], 1);
            srt[p] = rec[j];
            skey[p] = (unsigned short)key8[j];
        }
    }
    __syncthreads();

    // coalesced write-out: consecutive i -> consecutive global addr per run
    for (int i = tid; i < total; i += 1024) {
        int k = skey[i];
        int r = i - bstart[k];
        if (r < glim[k]) recs[gpos[k] + r] = srt[i];
    }
}

// One block per 32-row bucket (256 thr = 4 waves, wave wv -> rows wv*8..+7).
// Stage records in LDS, counting-sort FULL records by row (32 keys), then
// 8x-unrolled independent gathers from the unified pre, register accumulate,
// fused bias+relu writeout. (Verbatim champion: measured 61-62.7us.)
__global__ __launch_bounds__(256, 6) void aggregate9_kernel(
    const int* __restrict__ cur, const int2* __restrict__ recs,
    const unsigned short* __restrict__ pre,
    const float* __restrict__ bias,
    float* __restrict__ out, int N)
{
    __shared__ int2 srec[ACAP];             // 11.3 KB staged raw
    __shared__ int2 srt[ACAP];              // 11.3 KB row-sorted
    __shared__ int lcnt[32];
    __shared__ int lstart[32];
    __shared__ int lcur[32];

    const int b = blockIdx.x;
    const int tid = threadIdx.x;

    int n0 = cur[2 * b];     if (n0 > BCAP) n0 = BCAP;
    int n1 = cur[2 * b + 1]; if (n1 > BCAP) n1 = BCAP;
    const int total = n0 + n1;
    const int base0 = (2 * b) * BCAP, base1 = (2 * b + 1) * BCAP;

    if (tid < 32) lcnt[tid] = 0;
    __syncthreads();

    // stage + per-row counts (int LDS atomics)
    for (int i = tid; i < total; i += 256) {
        int2 r = (i < n0) ? recs[base0 + i] : recs[base1 + i - n0];
        srec[i] = r;
        atomicAdd(&lcnt[(r.x >> 17) & 31], 1);
    }
    __syncthreads();

    // wave 0 lanes 0-31: shfl exclusive scan of 32 counters
    if (tid < 32) {
        int cme = lcnt[tid];
        int p = cme;
#pragma unroll
        for (int o = 1; o < 32; o <<= 1) {
            int t = __shfl_up(p, o);
            if (tid >= o) p += t;
        }
        lstart[tid] = p - cme;
        lcur[tid] = p - cme;
    }
    __syncthreads();

    // scatter full records sorted by row
    for (int i = tid; i < total; i += 256) {
        int2 r = srec[i];
        srt[atomicAdd(&lcur[(r.x >> 17) & 31], 1)] = r;
    }
    __syncthreads();

    // gather: wave wv owns rows wv*8 .. wv*8+7; both adjacencies in one run
    const int wv = tid >> 6;
    const int lane = tid & 63;
    const float2 bi = *(const float2*)&bias[lane * 2];

#define GA(r) (*(const unsigned*)&pre[((r).x & 0x1ffff) * 128 + 2 * lane])
#define ACC(r, u) { float v = __int_as_float((r).y);                    \
        acc.x = fmaf(v, __uint_as_float((u) << 16), acc.x);             \
        acc.y = fmaf(v, __uint_as_float((u) & 0xffff0000u), acc.y); }

    for (int t = 0; t < 8; ++t) {
        const int rl = wv * 8 + t;
        const int s = lstart[rl];
        const int e = s + lcnt[rl];
        float2 acc = make_float2(0.f, 0.f);
        int j = s;
        for (; j + 8 <= e; j += 8) {
            int2 r0 = srt[j], r1 = srt[j + 1], r2 = srt[j + 2], r3 = srt[j + 3];
            int2 r4 = srt[j + 4], r5 = srt[j + 5], r6 = srt[j + 6], r7 = srt[j + 7];
            unsigned u0 = GA(r0), u1 = GA(r1), u2 = GA(r2), u3 = GA(r3);
            unsigned u4 = GA(r4), u5 = GA(r5), u6 = GA(r6), u7 = GA(r7);
            ACC(r0, u0); ACC(r1, u1); ACC(r2, u2); ACC(r3, u3);
            ACC(r4, u4); ACC(r5, u5); ACC(r6, u6); ACC(r7, u7);
        }
        for (; j + 4 <= e; j += 4) {
            int2 r0 = srt[j], r1 = srt[j + 1], r2 = srt[j + 2], r3 = srt[j + 3];
            unsigned u0 = GA(r0), u1 = GA(r1), u2 = GA(r2), u3 = GA(r3);
            ACC(r0, u0); ACC(r1, u1); ACC(r2, u2); ACC(r3, u3);
        }
        for (; j < e; ++j) {
            int2 r0 = srt[j];
            unsigned u0 = GA(r0);
            ACC(r0, u0);
        }
        int row = b * BROWS + rl;
        if (row < N) {
            float2 o;
            o.x = fmaxf(acc.x + bi.x, 0.f);
            o.y = fmaxf(acc.y + bi.y, 0.f);
            *(float2*)&out[row * 128 + 2 * lane] = o;
        }
    }
#undef GA
#undef ACC
}

extern "C" void kernel_launch(void* const* d_in, const int* in_sizes, int n_in,
                              void* d_out, int out_size, void* d_ws, size_t ws_size,
                              hipStream_t stream) {
    const float* x    = (const float*)d_in[0];
    const float* W0   = (const float*)d_in[1];
    const float* W1   = (const float*)d_in[2];
    const float* bias = (const float*)d_in[3];
    const float* ev0  = (const float*)d_in[4];
    const float* ev1  = (const float*)d_in[5];
    const int*   ei0  = (const int*)d_in[6];
    const int*   ei1  = (const int*)d_in[7];
    float* out = (float*)d_out;

    const int N = in_sizes[0] / 128;      // 50000
    const int E = in_sizes[4];            // 800000
    const int NBINS2 = NBUCK * 2;         // 3126

    // Workspace layout
    char* w = (char*)d_ws;
    unsigned short* pre = (unsigned short*)w;   w += (size_t)2 * PREROWS * 128 * 2;  // 33.5 MB
    unsigned short* wt0 = (unsigned short*)w;   w += (size_t)128 * 128 * 2;
    unsigned short* wt1 = (unsigned short*)w;   w += (size_t)128 * 128 * 2;
    int* cur = (int*)w;                         w += (size_t)NBINS2 * 4;
    int2* recs = (int2*)w;                      w += (size_t)NBINS2 * BCAP * 8;      // 17.6 MB

    // Phase 0: W -> bf16 transposed + zero cur (one 9-block dispatch)
    prep_kernel<<<9, 256, 0, stream>>>(W0, W1, wt0, wt1, cur, NBINS2);

    // Phase 1: fused MFMA GEMM (x converted once per block in LDS)
    gemm_fused_kernel<<<N / 16, 512, 0, stream>>>(x, wt0, wt1, pre, N);

    // Phase 2: LDS counting-sort fill (grid (98,2), coalesced write-out)
    dim3 fgrid((E + FT5 - 1) / FT5, 2);
    fill5_kernel<<<fgrid, 1024, 0, stream>>>(ei0, ei1, ev0, ev1, cur, recs, E);

    // Phase 3: bucket-sorted gather aggregation + bias + relu
    aggregate9_kernel<<<NBUCK, 256, 0, stream>>>(cur, recs, pre, bias, out, N);
}